// Round 1
// baseline (209.722 us; speedup 1.0000x reference)
//
#include <hip/hip_runtime.h>

#define BB 4096
#define SS 200
#define DD 128
#define HH 64
#define SP 208          // S padded to 13*16
#define LXPAD 136       // lX row stride (bf16 elems): 272B = 16B-aligned rows
#define OUTW (DD + 1)

typedef __attribute__((ext_vector_type(4))) float f32x4;
typedef __attribute__((ext_vector_type(8))) __bf16 bf16x8;
typedef __attribute__((ext_vector_type(4))) short s16x4;

__device__ __forceinline__ short f2b(float f) {        // f32 -> bf16 (RNE)
  unsigned int u = __float_as_uint(f);
  unsigned int r = (u + 0x7FFFu + ((u >> 16) & 1u)) >> 16;
  return (short)r;
}
__device__ __forceinline__ float b2f(short h) {
  return __uint_as_float(((unsigned int)(unsigned short)h) << 16);
}

// ---------------- setup: P = pos@Wp, We -> MFMA B-frag order, mask dtype probe ----
__global__ void setup_kernel(const float* __restrict__ pos,
                             const float* __restrict__ Wp,
                             const float* __restrict__ We,
                             const void* __restrict__ maskv,
                             float* __restrict__ Pmat,
                             short* __restrict__ Bfrag,
                             int* __restrict__ flag) {
  __shared__ int anyf[4];
  const int blk = blockIdx.x;
  const int t = threadIdx.x;
  if (blk < SS) {
    if (t < HH) {
      float acc = 0.f;
      #pragma unroll 8
      for (int d = 0; d < DD; ++d) acc = fmaf(pos[blk * DD + d], Wp[d * HH + t], acc);
      Pmat[blk * HH + t] = acc;
    }
  } else if (blk == SS) {
    // Bfrag[((ct*4+kt)*64+lane)*8 + j] = bf16(We[kt*32 + 8*(lane>>4) + j][ct*16 + (lane&15)])
    for (int id = t; id < 1024; id += 256) {
      int lane = id & 63;
      int kt = (id >> 6) & 3;
      int ct = id >> 8;
      int kbase = kt * 32 + 8 * (lane >> 4);
      int n = ct * 16 + (lane & 15);
      short* dst = Bfrag + id * 8;
      #pragma unroll
      for (int j = 0; j < 8; ++j) dst[j] = f2b(We[(kbase + j) * HH + n]);
    }
  } else {
    // mask dtype probe: bool8 has nonzero bytes at positions %4!=0; int32(0/1) does not
    const unsigned char* mb = (const unsigned char*)maskv;
    int local = 0;
    for (int i = t; i < 4096; i += 256)
      if ((i & 3) != 0 && mb[i] != 0) local = 1;
    unsigned long long bal = __ballot(local != 0);
    if ((t & 63) == 0) anyf[t >> 6] = (bal != 0ull) ? 1 : 0;
    __syncthreads();
    if (t == 0) *flag = (anyf[0] | anyf[1] | anyf[2] | anyf[3]);
  }
}

// ---------------- fused main kernel: one block per batch row ----------------
__global__ __launch_bounds__(256, 2) void fused_kernel(
    const float* __restrict__ Xs, const float* __restrict__ Xi,
    const void* __restrict__ maskv, const float* __restrict__ Wc,
    const float* __restrict__ zv, const float* __restrict__ Pmat,
    const short* __restrict__ Bfrag, const int* __restrict__ flagp,
    float* __restrict__ out) {
  __shared__ __align__(16) short lX[SP * LXPAD];   // 56,576 B
  __shared__ float sc_lds[SS];
  __shared__ float c_lds[HH];
  __shared__ float z_lds[HH];
  __shared__ float red[12];
  __shared__ float psum[8 * DD];

  const int t = threadIdx.x;
  const int b = blockIdx.x;
  const int lane = t & 63;
  const int w = t >> 6;

  // ---- stage X_series[b] -> LDS bf16 (coalesced float4) ----
  const float* xrow = Xs + (size_t)b * (SS * DD);
  #pragma unroll 5
  for (int f = t; f < SS * DD / 4; f += 256) {
    const f32x4 v = *(const f32x4*)(xrow + 4 * f);
    int r = f >> 5;            // row = (4f)/128
    int c = (f & 31) * 4;
    s16x4 h;
    h.x = f2b(v.x); h.y = f2b(v.y); h.z = f2b(v.z); h.w = f2b(v.w);
    *(s16x4*)&lX[r * LXPAD + c] = h;
  }
  for (int i = t; i < 8 * LXPAD; i += 256) lX[SS * LXPAD + i] = 0;  // zero pad rows 200..207

  // ---- B fragments (held in regs for the whole block) ----
  bf16x8 bf[4][4];
  {
    const bf16x8* bp = (const bf16x8*)Bfrag;
    #pragma unroll
    for (int ct = 0; ct < 4; ++ct)
      #pragma unroll
      for (int kt = 0; kt < 4; ++kt)
        bf[ct][kt] = bp[(ct * 4 + kt) * 64 + lane];
  }

  // ---- c[h] = X_item[b] . Wc[:,h] (wave 0), z -> LDS ----
  if (t < HH) {
    const float* xi = Xi + (size_t)b * DD;
    float acc = 0.f;
    #pragma unroll 8
    for (int d = 0; d < DD; ++d) acc = fmaf(xi[d], Wc[d * HH + t], acc);
    c_lds[t] = acc;
  } else if (t < 2 * HH) {
    z_lds[t - HH] = zv[t - HH];
  }
  __syncthreads();

  // ---- E = Xb @ We via MFMA, then scores[s] = sum_h z[h]*tanh(c+P+E) ----
  const int lg = lane >> 4;
  const int lr = lane & 15;
  for (int rt = w; rt < SP / 16; rt += 4) {
    bf16x8 af[4];
    const short* abase = &lX[(rt * 16 + lr) * LXPAD];
    #pragma unroll
    for (int kt = 0; kt < 4; ++kt)
      af[kt] = *(const bf16x8*)&abase[kt * 32 + 8 * lg];
    f32x4 acc[4];
    #pragma unroll
    for (int ct = 0; ct < 4; ++ct) acc[ct] = (f32x4){0.f, 0.f, 0.f, 0.f};
    #pragma unroll
    for (int kt = 0; kt < 4; ++kt)
      #pragma unroll
      for (int ct = 0; ct < 4; ++ct)
        acc[ct] = __builtin_amdgcn_mfma_f32_16x16x32_bf16(af[kt], bf[ct][kt], acc[ct], 0, 0, 0);
    // D map (HW-verified): col = lane&15, row = (lane>>4)*4 + reg
    #pragma unroll
    for (int r = 0; r < 4; ++r) {
      int s = rt * 16 + lg * 4 + r;
      float partial = 0.f;
      if (s < SS) {
        #pragma unroll
        for (int ct = 0; ct < 4; ++ct) {
          int h = ct * 16 + lr;
          float pre = c_lds[h] + Pmat[s * HH + h] + acc[ct][r];
          float e2 = __expf(2.f * pre);                 // tanh = 1 - 2/(e^{2x}+1), inf-safe
          partial = fmaf(z_lds[h], 1.f - 2.f / (e2 + 1.f), partial);
        }
      }
      partial += __shfl_xor(partial, 1);
      partial += __shfl_xor(partial, 2);
      partial += __shfl_xor(partial, 4);
      partial += __shfl_xor(partial, 8);
      if (lr == 0 && s < SS) sc_lds[s] = partial;
    }
  }
  __syncthreads();

  // ---- masked softmax over s + raw masked score sum ----
  bool valid = false;
  float myscore = 0.f;
  float vsc = -__builtin_inff();
  if (t < SS) {
    int mv;
    if (*flagp) mv = ((const unsigned char*)maskv)[(size_t)b * SS + t];
    else        mv = ((const int*)maskv)[(size_t)b * SS + t];
    valid = (mv != 0);
    myscore = sc_lds[t];
    if (valid) vsc = myscore;
  }
  float m = vsc;
  #pragma unroll
  for (int off = 1; off <= 32; off <<= 1) m = fmaxf(m, __shfl_xor(m, off));
  if (lane == 0) red[w] = m;
  __syncthreads();
  m = fmaxf(fmaxf(red[0], red[1]), fmaxf(red[2], red[3]));
  float e = valid ? __expf(vsc - m) : 0.f;
  float sv = valid ? myscore : 0.f;
  float se = e, ssv = sv;
  #pragma unroll
  for (int off = 1; off <= 32; off <<= 1) {
    se += __shfl_xor(se, off);
    ssv += __shfl_xor(ssv, off);
  }
  if (lane == 0) { red[4 + w] = se; red[8 + w] = ssv; }
  __syncthreads();
  float denom = (red[4] + red[5]) + (red[6] + red[7]);
  if (t < SS) sc_lds[t] = e / denom;                       // attn (overwrite scores)
  if (t == 0) out[(size_t)b * OUTW + DD] = (red[8] + red[9]) + (red[10] + red[11]);
  __syncthreads();

  // ---- attention_output[d] = sum_s attn[s] * X[s][d] ----
  {
    const int d0 = (t & 31) * 4;
    const int ch = t >> 5;                                 // 8 chunks of 25 s-rows
    float a0 = 0.f, a1 = 0.f, a2 = 0.f, a3 = 0.f;
    #pragma unroll 5
    for (int i = 0; i < 25; ++i) {
      int s = ch * 25 + i;
      float wsc = sc_lds[s];
      s16x4 v = *(const s16x4*)&lX[s * LXPAD + d0];
      a0 = fmaf(wsc, b2f(v.x), a0);
      a1 = fmaf(wsc, b2f(v.y), a1);
      a2 = fmaf(wsc, b2f(v.z), a2);
      a3 = fmaf(wsc, b2f(v.w), a3);
    }
    psum[ch * DD + d0 + 0] = a0;
    psum[ch * DD + d0 + 1] = a1;
    psum[ch * DD + d0 + 2] = a2;
    psum[ch * DD + d0 + 3] = a3;
  }
  __syncthreads();
  if (t < DD) {
    float o = 0.f;
    #pragma unroll
    for (int chh = 0; chh < 8; ++chh) o += psum[chh * DD + t];
    out[(size_t)b * OUTW + t] = o;
  }
}

extern "C" void kernel_launch(void* const* d_in, const int* in_sizes, int n_in,
                              void* d_out, int out_size, void* d_ws, size_t ws_size,
                              hipStream_t stream) {
  const float* Xs  = (const float*)d_in[0];   // X_series [B,S,D]
  const float* pos = (const float*)d_in[1];   // pos_series [S,D]
  const float* Xi  = (const float*)d_in[2];   // X_item [B,D]
  const void*  mk  = d_in[3];                 // valid_mask [B,S] (bool8 or int32 — probed)
  const float* Wc  = (const float*)d_in[4];
  const float* Wp  = (const float*)d_in[5];
  const float* We  = (const float*)d_in[6];
  const float* zv  = (const float*)d_in[7];
  float* out = (float*)d_out;

  char* ws = (char*)d_ws;
  int*   flag  = (int*)ws;                       // 4 B @ 0
  float* Pmat  = (float*)(ws + 256);             // 200*64*4 = 51200 B
  short* Bfrag = (short*)(ws + 256 + SS * HH * 4); // 16384 B

  setup_kernel<<<SS + 2, 256, 0, stream>>>(pos, Wp, We, mk, Pmat, Bfrag, flag);
  fused_kernel<<<BB, 256, 0, stream>>>(Xs, Xi, mk, Wc, zv, Pmat, Bfrag, flag, out);
}

// Round 2
// 204.253 us; speedup vs baseline: 1.0268x; 1.0268x over previous
//
#include <hip/hip_runtime.h>

#define BB 4096
#define SS 200
#define DD 128
#define HH 64
#define OUTW (DD + 1)

typedef __attribute__((ext_vector_type(4))) float f32x4;
typedef __attribute__((ext_vector_type(8))) __bf16 bf16x8;

__device__ __forceinline__ short f2b(float f) {        // f32 -> bf16 (RNE)
  unsigned int u = __float_as_uint(f);
  unsigned int r = (u + 0x7FFFu + ((u >> 16) & 1u)) >> 16;
  return (short)r;
}

// ---------------- setup: P = pos@Wp, We -> MFMA B-frag order, mask dtype probe ----
__global__ void setup_kernel(const float* __restrict__ pos,
                             const float* __restrict__ Wp,
                             const float* __restrict__ We,
                             const void* __restrict__ maskv,
                             float* __restrict__ Pmat,
                             short* __restrict__ Bfrag,
                             int* __restrict__ flag) {
  __shared__ int anyf[4];
  const int blk = blockIdx.x;
  const int t = threadIdx.x;
  if (blk < SS) {
    if (t < HH) {
      float acc = 0.f;
      #pragma unroll 8
      for (int d = 0; d < DD; ++d) acc = fmaf(pos[blk * DD + d], Wp[d * HH + t], acc);
      Pmat[blk * HH + t] = acc;
    }
  } else if (blk == SS) {
    // Bfrag[((ct*4+kt)*64+lane)*8 + j] = bf16(We[kt*32 + 8*(lane>>4) + j][ct*16 + (lane&15)])
    for (int id = t; id < 1024; id += 256) {
      int lane = id & 63;
      int kt = (id >> 6) & 3;
      int ct = id >> 8;
      int kbase = kt * 32 + 8 * (lane >> 4);
      int n = ct * 16 + (lane & 15);
      short* dst = Bfrag + id * 8;
      #pragma unroll
      for (int j = 0; j < 8; ++j) dst[j] = f2b(We[(kbase + j) * HH + n]);
    }
  } else {
    // mask dtype probe: bool8 has nonzero bytes at positions %4!=0; int32(0/1) does not
    const unsigned char* mb = (const unsigned char*)maskv;
    int local = 0;
    for (int i = t; i < 4096; i += 256)
      if ((i & 3) != 0 && mb[i] != 0) local = 1;
    unsigned long long bal = __ballot(local != 0);
    if ((t & 63) == 0) anyf[t >> 6] = (bal != 0ull) ? 1 : 0;
    __syncthreads();
    if (t == 0) *flag = (anyf[0] | anyf[1] | anyf[2] | anyf[3]);
  }
}

// MFMA + score epilogue for one 16-row tile whose A-fragments live in regs.
__device__ __forceinline__ void do_tile(const bf16x8* af, int tile, int lane, int lg, int lr,
                                        const short* bf_lds, const float* __restrict__ Pmat,
                                        const float* c_lds, const float* z_lds,
                                        float* sc_lds) {
  f32x4 acc[4];
  const int s0 = tile * 16 + lg * 4;
  // C-init with P[s,h] + c[h]  (D layout: col h = lane&15, row s = (lane>>4)*4 + r)
  #pragma unroll
  for (int ct = 0; ct < 4; ++ct) {
    const int h = ct * 16 + lr;
    const float chv = c_lds[h];
    #pragma unroll
    for (int r = 0; r < 4; ++r) {
      int sp = s0 + r; if (sp >= SS) sp = SS - 1;   // clamped rows are write-guarded below
      acc[ct][r] = Pmat[sp * HH + h] + chv;
    }
  }
  const bf16x8* bp = (const bf16x8*)bf_lds;
  #pragma unroll
  for (int kt = 0; kt < 4; ++kt)
    #pragma unroll
    for (int ct = 0; ct < 4; ++ct)
      acc[ct] = __builtin_amdgcn_mfma_f32_16x16x32_bf16(af[kt], bp[(ct * 4 + kt) * 64 + lane],
                                                        acc[ct], 0, 0, 0);
  // scores[s] = sum_h z[h] * tanh(pre);  tanh = 1 - 2*rcp(e^{2x}+1)  (inf-safe)
  #pragma unroll
  for (int r = 0; r < 4; ++r) {
    float part = 0.f;
    #pragma unroll
    for (int ct = 0; ct < 4; ++ct) {
      const float e2 = __expf(2.f * acc[ct][r]);
      const float th = 1.f - 2.f * __builtin_amdgcn_rcpf(e2 + 1.f);
      part = fmaf(z_lds[ct * 16 + lr], th, part);
    }
    part += __shfl_xor(part, 1);
    part += __shfl_xor(part, 2);
    part += __shfl_xor(part, 4);
    part += __shfl_xor(part, 8);
    if (lr == 0 && s0 + r < SS) sc_lds[s0 + r] = part;
  }
}

// ---------------- fused main kernel: one block (512 thr, 8 waves) per batch row ----
__global__ __launch_bounds__(512, 4) void fused_kernel(
    const float* __restrict__ Xs, const float* __restrict__ Xi,
    const void* __restrict__ maskv, const float* __restrict__ Wc,
    const float* __restrict__ zv, const float* __restrict__ Pmat,
    const short* __restrict__ Bfrag, const int* __restrict__ flagp,
    float* __restrict__ out) {
  __shared__ __align__(16) short bf_lds[16 * 64 * 8];   // 16 KB: We B-fragments
  __shared__ float sc_lds[208];
  __shared__ float c_lds[HH];
  __shared__ float cpart[8][HH];
  __shared__ float z_lds[HH];
  __shared__ float red[24];
  __shared__ float psum[8 * DD];

  const int t = threadIdx.x;
  const int b = blockIdx.x;
  const int lane = t & 63;
  const int w = t >> 6;
  const int lg = lane >> 4;
  const int lr = lane & 15;
  const bool hasB = (w < 5);        // 13 tiles: wave w owns tile w, and tile 8+w if w<5
  const int tA = w, tB = 8 + w;

  const float* xb = Xs + (size_t)b * (SS * DD);

  // ---- stage X rows directly into register A-fragments (wave-private, no barrier) ----
  bf16x8 afA[4], afB[4];
  {
    const float* rA = xb + (tA * 16 + lr) * DD;       // row < 128 always valid
    f32x4 l0[4], l1[4];
    #pragma unroll
    for (int kt = 0; kt < 4; ++kt) {
      l0[kt] = *(const f32x4*)(rA + kt * 32 + lg * 8);
      l1[kt] = *(const f32x4*)(rA + kt * 32 + lg * 8 + 4);
    }
    #pragma unroll
    for (int kt = 0; kt < 4; ++kt) {
      bf16x8 v;
      v[0]=(__bf16)l0[kt][0]; v[1]=(__bf16)l0[kt][1]; v[2]=(__bf16)l0[kt][2]; v[3]=(__bf16)l0[kt][3];
      v[4]=(__bf16)l1[kt][0]; v[5]=(__bf16)l1[kt][1]; v[6]=(__bf16)l1[kt][2]; v[7]=(__bf16)l1[kt][3];
      afA[kt] = v;
    }
  }
  {
    const int sB = tB * 16 + lr;
    const bool vB = hasB && (sB < SS);
    f32x4 l0[4], l1[4];
    if (vB) {
      const float* rB = xb + sB * DD;
      #pragma unroll
      for (int kt = 0; kt < 4; ++kt) {
        l0[kt] = *(const f32x4*)(rB + kt * 32 + lg * 8);
        l1[kt] = *(const f32x4*)(rB + kt * 32 + lg * 8 + 4);
      }
    } else {
      #pragma unroll
      for (int kt = 0; kt < 4; ++kt) {
        l0[kt] = (f32x4){0.f,0.f,0.f,0.f};
        l1[kt] = (f32x4){0.f,0.f,0.f,0.f};
      }
    }
    #pragma unroll
    for (int kt = 0; kt < 4; ++kt) {
      bf16x8 v;
      v[0]=(__bf16)l0[kt][0]; v[1]=(__bf16)l0[kt][1]; v[2]=(__bf16)l0[kt][2]; v[3]=(__bf16)l0[kt][3];
      v[4]=(__bf16)l1[kt][0]; v[5]=(__bf16)l1[kt][1]; v[6]=(__bf16)l1[kt][2]; v[7]=(__bf16)l1[kt][3];
      afB[kt] = v;
    }
  }

  // ---- B-fragments global -> LDS (16 KB, L2-hot), c = Xi@Wc partials, z ----
  {
    const f32x4* src = (const f32x4*)Bfrag;
    f32x4* dst = (f32x4*)bf_lds;
    dst[t] = src[t];
    dst[t + 512] = src[t + 512];
  }
  {
    const int h = t & 63, ch = t >> 6;
    const float* xi = Xi + (size_t)b * DD + ch * 16;
    const float* wc = Wc + (size_t)(ch * 16) * HH + h;
    float a = 0.f;
    #pragma unroll
    for (int d = 0; d < 16; ++d) a = fmaf(xi[d], wc[d * HH], a);
    cpart[ch][h] = a;
  }
  if (t < HH) z_lds[t] = zv[t];
  if (t >= SS && t < 208) sc_lds[t] = 0.f;     // pad rows: zero attn weight
  __syncthreads();
  if (t < HH) {
    float a = 0.f;
    #pragma unroll
    for (int ch = 0; ch < 8; ++ch) a += cpart[ch][t];
    c_lds[t] = a;
  }
  __syncthreads();

  // ---- scores via MFMA ----
  do_tile(afA, tA, lane, lg, lr, bf_lds, Pmat, c_lds, z_lds, sc_lds);
  if (hasB) do_tile(afB, tB, lane, lg, lr, bf_lds, Pmat, c_lds, z_lds, sc_lds);
  __syncthreads();

  // ---- masked softmax + raw masked score sum ----
  bool valid = false;
  float myscore = 0.f, vsc = -__builtin_inff();
  if (t < SS) {
    int mv;
    if (*flagp) mv = ((const unsigned char*)maskv)[(size_t)b * SS + t];
    else        mv = ((const int*)maskv)[(size_t)b * SS + t];
    valid = (mv != 0);
    myscore = sc_lds[t];
    if (valid) vsc = myscore;
  }
  float m = vsc;
  #pragma unroll
  for (int off = 1; off <= 32; off <<= 1) m = fmaxf(m, __shfl_xor(m, off));
  if (lane == 0) red[w] = m;
  __syncthreads();
  m = red[0];
  #pragma unroll
  for (int ww = 1; ww < 8; ++ww) m = fmaxf(m, red[ww]);
  const float e = valid ? __expf(vsc - m) : 0.f;
  const float sv = valid ? myscore : 0.f;
  float se = e, ssv = sv;
  #pragma unroll
  for (int off = 1; off <= 32; off <<= 1) { se += __shfl_xor(se, off); ssv += __shfl_xor(ssv, off); }
  if (lane == 0) { red[8 + w] = se; red[16 + w] = ssv; }
  __syncthreads();
  float denom = 0.f, ssum = 0.f;
  #pragma unroll
  for (int ww = 0; ww < 8; ++ww) { denom += red[8 + ww]; ssum += red[16 + ww]; }
  if (t < SS) sc_lds[t] = e / denom;          // attn weights
  if (t == 0) out[(size_t)b * OUTW + DD] = ssum;
  __syncthreads();

  // ---- attention_output from register fragments ----
  float part[4][8];
  #pragma unroll
  for (int kt = 0; kt < 4; ++kt)
    #pragma unroll
    for (int j = 0; j < 8; ++j) part[kt][j] = 0.f;
  {
    const float wA = sc_lds[tA * 16 + lr];
    #pragma unroll
    for (int kt = 0; kt < 4; ++kt)
      #pragma unroll
      for (int j = 0; j < 8; ++j)
        part[kt][j] = fmaf(wA, (float)afA[kt][j], part[kt][j]);
  }
  if (hasB) {
    const float wB = sc_lds[tB * 16 + lr];    // rows >= 200 have weight 0
    #pragma unroll
    for (int kt = 0; kt < 4; ++kt)
      #pragma unroll
      for (int j = 0; j < 8; ++j)
        part[kt][j] = fmaf(wB, (float)afB[kt][j], part[kt][j]);
  }
  #pragma unroll
  for (int off = 1; off <= 8; off <<= 1)
    #pragma unroll
    for (int kt = 0; kt < 4; ++kt)
      #pragma unroll
      for (int j = 0; j < 8; ++j)
        part[kt][j] += __shfl_xor(part[kt][j], off);
  if (lr == 0) {
    #pragma unroll
    for (int kt = 0; kt < 4; ++kt)
      #pragma unroll
      for (int j = 0; j < 8; ++j)
        psum[w * DD + kt * 32 + lg * 8 + j] = part[kt][j];
  }
  __syncthreads();
  if (t < DD) {
    float o = 0.f;
    #pragma unroll
    for (int ww = 0; ww < 8; ++ww) o += psum[ww * DD + t];
    out[(size_t)b * OUTW + t] = o;
  }
}

extern "C" void kernel_launch(void* const* d_in, const int* in_sizes, int n_in,
                              void* d_out, int out_size, void* d_ws, size_t ws_size,
                              hipStream_t stream) {
  const float* Xs  = (const float*)d_in[0];   // X_series [B,S,D]
  const float* pos = (const float*)d_in[1];   // pos_series [S,D]
  const float* Xi  = (const float*)d_in[2];   // X_item [B,D]
  const void*  mk  = d_in[3];                 // valid_mask [B,S] (bool8 or int32 — probed)
  const float* Wc  = (const float*)d_in[4];
  const float* Wp  = (const float*)d_in[5];
  const float* We  = (const float*)d_in[6];
  const float* zv  = (const float*)d_in[7];
  float* out = (float*)d_out;

  char* ws = (char*)d_ws;
  int*   flag  = (int*)ws;                          // 4 B @ 0
  float* Pmat  = (float*)(ws + 256);                // 200*64*4 = 51200 B
  short* Bfrag = (short*)(ws + 256 + SS * HH * 4);  // 16384 B

  setup_kernel<<<SS + 2, 256, 0, stream>>>(pos, Wp, We, mk, Pmat, Bfrag, flag);
  fused_kernel<<<BB, 512, 0, stream>>>(Xs, Xi, mk, Wc, zv, Pmat, Bfrag, flag, out);
}

// Round 3
// 196.216 us; speedup vs baseline: 1.0688x; 1.0410x over previous
//
#include <hip/hip_runtime.h>

#define BB 4096
#define SS 200
#define DD 128
#define HH 64
#define NT 13            // 13 tiles of 16 rows (208 padded)
#define OUTW (DD + 1)

typedef __attribute__((ext_vector_type(4))) float f32x4;
typedef __attribute__((ext_vector_type(8))) __bf16 bf16x8;

__device__ __forceinline__ short f2b(float f) {        // f32 -> bf16 (RNE)
  unsigned int u = __float_as_uint(f);
  unsigned int r = (u + 0x7FFFu + ((u >> 16) & 1u)) >> 16;
  return (short)r;
}

// ---------------- setup1: P = pos@Wp, We -> MFMA B-frag order, mask dtype probe ----
__global__ void setup_kernel(const float* __restrict__ pos,
                             const float* __restrict__ Wp,
                             const float* __restrict__ We,
                             const void* __restrict__ maskv,
                             float* __restrict__ Pmat,
                             short* __restrict__ Bfrag,
                             int* __restrict__ flag) {
  __shared__ int anyf[4];
  const int blk = blockIdx.x;
  const int t = threadIdx.x;
  if (blk < SS) {
    if (t < HH) {
      float acc = 0.f;
      #pragma unroll 8
      for (int d = 0; d < DD; ++d) acc = fmaf(pos[blk * DD + d], Wp[d * HH + t], acc);
      Pmat[blk * HH + t] = acc;
    }
  } else if (blk == SS) {
    // Bfrag[((ct*4+kt)*64+lane)*8 + j] = bf16(We[kt*32 + 8*(lane>>4) + j][ct*16 + (lane&15)])
    for (int id = t; id < 1024; id += 256) {
      int lane = id & 63;
      int kt = (id >> 6) & 3;
      int ct = id >> 8;
      int kbase = kt * 32 + 8 * (lane >> 4);
      int n = ct * 16 + (lane & 15);
      short* dst = Bfrag + id * 8;
      #pragma unroll
      for (int j = 0; j < 8; ++j) dst[j] = f2b(We[(kbase + j) * HH + n]);
    }
  } else {
    // mask dtype probe: bool8 has nonzero bytes at positions %4!=0; int32(0/1) does not
    const unsigned char* mb = (const unsigned char*)maskv;
    int local = 0;
    for (int i = t; i < 4096; i += 256)
      if ((i & 3) != 0 && mb[i] != 0) local = 1;
    unsigned long long bal = __ballot(local != 0);
    if ((t & 63) == 0) anyf[t >> 6] = (bal != 0ull) ? 1 : 0;
    __syncthreads();
    if (t == 0) *flag = (anyf[0] | anyf[1] | anyf[2] | anyf[3]);
  }
}

// ---------------- setup2: swizzle Pmat into per-lane-contiguous layout -------------
// Psw[(((t*4+lg)*16+lr)*16 + ct*4 + r)] = Pmat[min(t*16+4lg+r,199)][16ct+lr]
__global__ void swizzle_kernel(const float* __restrict__ Pmat, float* __restrict__ Psw) {
  const int t = blockIdx.x;                 // tile 0..12
  const int tid = threadIdx.x;              // 256
  const int lg = tid >> 6, lr = (tid >> 2) & 15, ct = tid & 3;
  f32x4 v;
  #pragma unroll
  for (int r = 0; r < 4; ++r) {
    int s = t * 16 + 4 * lg + r;
    if (s >= SS) s = SS - 1;
    v[r] = Pmat[s * HH + ct * 16 + lr];
  }
  *(f32x4*)&Psw[((t * 4 + lg) * 16 + lr) * 16 + ct * 4] = v;
}

// ---------------- fused: one WAVE per batch row, streaming, no softmax barrier -----
__global__ __launch_bounds__(256, 3) void fused_kernel(
    const float* __restrict__ Xs, const float* __restrict__ Xi,
    const void* __restrict__ maskv, const float* __restrict__ Wc,
    const float* __restrict__ zv, const float* __restrict__ Psw,
    const short* __restrict__ Bfrag, const int* __restrict__ flagp,
    float* __restrict__ out) {
  __shared__ __align__(16) short bf_lds[16 * 64 * 8];   // 16 KB We B-fragments

  const int t = threadIdx.x;
  const int lane = t & 63;
  const int w = t >> 6;
  const int lg = lane >> 4;
  const int lr = lane & 15;
  const int b = blockIdx.x * 4 + w;

  // stage B-fragments (L3-hot 16 KB)
  {
    const f32x4* src = (const f32x4*)Bfrag;
    f32x4* dst = (f32x4*)bf_lds;
    #pragma unroll
    for (int i = 0; i < 4; ++i) dst[t + 256 * i] = src[t + 256 * i];
  }
  __syncthreads();

  // c[h] = Xi[b] . Wc[:,h], h = lane; then redistribute c,z to (ct,lr) layout
  float c = 0.f;
  {
    const float* xi = Xi + (size_t)b * DD;
    const float* wc = Wc + lane;
    #pragma unroll 8
    for (int d = 0; d < DD; ++d) c = fmaf(xi[d], wc[d * HH], c);
  }
  float c4[4], z4[4];
  {
    const float zl = zv[lane];
    #pragma unroll
    for (int ct = 0; ct < 4; ++ct) {
      c4[ct] = __shfl(c, ct * 16 + lr, 64);
      z4[ct] = __shfl(zl, ct * 16 + lr, 64);
    }
  }
  const int mflag = *flagp;
  const unsigned char* mbp = (const unsigned char*)maskv + (size_t)b * SS;
  const int* mip = (const int*)maskv + (size_t)b * SS;
  const float* xb = Xs + (size_t)b * (SS * DD) + lg * 8;
  const bf16x8* bp = (const bf16x8*)bf_lds;

  float part[4][8];
  #pragma unroll
  for (int kt = 0; kt < 4; ++kt)
    #pragma unroll
    for (int j = 0; j < 8; ++j) part[kt][j] = 0.f;
  float usum = 0.f, ssum = 0.f;

  // prologue: load tile 0
  f32x4 raw[8];
  {
    const float* rp = xb + (size_t)lr * DD;      // tile 0 row = lr
    #pragma unroll
    for (int kt = 0; kt < 4; ++kt) {
      raw[2 * kt]     = *(const f32x4*)(rp + kt * 32);
      raw[2 * kt + 1] = *(const f32x4*)(rp + kt * 32 + 4);
    }
  }

  for (int tt = 0; tt < NT; ++tt) {
    // convert current tile to bf16 A-fragments
    bf16x8 af[4];
    #pragma unroll
    for (int kt = 0; kt < 4; ++kt) {
      bf16x8 v;
      v[0] = (__bf16)raw[2*kt][0]; v[1] = (__bf16)raw[2*kt][1];
      v[2] = (__bf16)raw[2*kt][2]; v[3] = (__bf16)raw[2*kt][3];
      v[4] = (__bf16)raw[2*kt+1][0]; v[5] = (__bf16)raw[2*kt+1][1];
      v[6] = (__bf16)raw[2*kt+1][2]; v[7] = (__bf16)raw[2*kt+1][3];
      af[kt] = v;
    }
    // prefetch next tile (overwrites raw; af already extracted)
    if (tt + 1 < NT) {
      int srow = (tt + 1) * 16 + lr;
      if (srow >= SS) srow = SS - 1;
      const float* rp = xb + (size_t)srow * DD;
      #pragma unroll
      for (int kt = 0; kt < 4; ++kt) {
        raw[2 * kt]     = *(const f32x4*)(rp + kt * 32);
        raw[2 * kt + 1] = *(const f32x4*)(rp + kt * 32 + 4);
      }
    }
    // C-init: pre-swizzled P + c   (D layout: h = ct*16+lr, s = tile*16 + 4lg + r)
    f32x4 acc[4];
    {
      const f32x4* pp = (const f32x4*)(Psw + ((tt * 4 + lg) * 16 + lr) * 16);
      #pragma unroll
      for (int ct = 0; ct < 4; ++ct) {
        f32x4 pv = pp[ct];
        acc[ct][0] = pv[0] + c4[ct]; acc[ct][1] = pv[1] + c4[ct];
        acc[ct][2] = pv[2] + c4[ct]; acc[ct][3] = pv[3] + c4[ct];
      }
    }
    #pragma unroll
    for (int kt = 0; kt < 4; ++kt)
      #pragma unroll
      for (int ct = 0; ct < 4; ++ct)
        acc[ct] = __builtin_amdgcn_mfma_f32_16x16x32_bf16(af[kt], bp[(ct * 4 + kt) * 64 + lane],
                                                          acc[ct], 0, 0, 0);
    // scores[s=tt*16+4lg+r] = sum_h z[h]*tanh(pre);  reduce over lr (h-groups)
    float sc[4];
    #pragma unroll
    for (int r = 0; r < 4; ++r) {
      float p = 0.f;
      #pragma unroll
      for (int ct = 0; ct < 4; ++ct) {
        const float e2 = __expf(2.f * acc[ct][r]);
        const float th = 1.f - 2.f * __builtin_amdgcn_rcpf(e2 + 1.f);
        p = fmaf(z4[ct], th, p);
      }
      p += __shfl_xor(p, 1);
      p += __shfl_xor(p, 2);
      p += __shfl_xor(p, 4);
      p += __shfl_xor(p, 8);
      sc[r] = p;      // full score, identical across the 16-lane lr group
    }
    // redistribute: this lane needs score of row s = tt*16 + lr  (held by lg' = lr>>2, reg lr&3)
    #pragma unroll
    for (int r = 0; r < 4; ++r) sc[r] = __shfl(sc[r], (lr >> 2) << 4, 64);
    const float sa = (lr & 1) ? sc[1] : sc[0];
    const float sb = (lr & 1) ? sc[3] : sc[2];
    const float mysc = (lr & 2) ? sb : sa;
    const int srow = tt * 16 + lr;
    int mv = 0;
    if (srow < SS) mv = mflag ? (int)mbp[srow] : mip[srow];
    const float u = mv ? __expf(mysc) : 0.f;    // |score| <= sum|z| ~ 7: no max-sub needed
    ssum += mv ? mysc : 0.f;
    usum += u;
    // accumulate u * x into per-lane partials (lane owns row lr, cols kt*32+lg*8+j)
    #pragma unroll
    for (int kt = 0; kt < 4; ++kt)
      #pragma unroll
      for (int j = 0; j < 8; ++j)
        part[kt][j] = fmaf(u, (float)af[kt][j], part[kt][j]);
  }

  // reduce over the 16 lr lanes (rows); each lg group covers distinct cols
  #pragma unroll
  for (int off = 1; off <= 8; off <<= 1) {
    #pragma unroll
    for (int kt = 0; kt < 4; ++kt)
      #pragma unroll
      for (int j = 0; j < 8; ++j)
        part[kt][j] += __shfl_xor(part[kt][j], off);
    usum += __shfl_xor(usum, off);
    ssum += __shfl_xor(ssum, off);
  }
  const float inv = 1.f / usum;
  if (lr == 0) {
    float* ob = out + (size_t)b * OUTW;
    #pragma unroll
    for (int kt = 0; kt < 4; ++kt)
      #pragma unroll
      for (int j = 0; j < 8; ++j)
        ob[kt * 32 + lg * 8 + j] = part[kt][j] * inv;
  }
  if (lane == 8) out[(size_t)b * OUTW + DD] = ssum;
}

extern "C" void kernel_launch(void* const* d_in, const int* in_sizes, int n_in,
                              void* d_out, int out_size, void* d_ws, size_t ws_size,
                              hipStream_t stream) {
  const float* Xs  = (const float*)d_in[0];   // X_series [B,S,D]
  const float* pos = (const float*)d_in[1];   // pos_series [S,D]
  const float* Xi  = (const float*)d_in[2];   // X_item [B,D]
  const void*  mk  = d_in[3];                 // valid_mask [B,S] (bool8 or int32 — probed)
  const float* Wc  = (const float*)d_in[4];
  const float* Wp  = (const float*)d_in[5];
  const float* We  = (const float*)d_in[6];
  const float* zv  = (const float*)d_in[7];
  float* out = (float*)d_out;

  char* ws = (char*)d_ws;
  int*   flag  = (int*)ws;                             // 4 B    @ 0
  float* Pmat  = (float*)(ws + 256);                   // 51200 B
  short* Bfrag = (short*)(ws + 256 + SS * HH * 4);     // 16384 B @ 51456
  float* Psw   = (float*)(ws + 256 + SS * HH * 4 + 16384);  // 53248 B @ 67840 (16B-aligned)

  setup_kernel<<<SS + 2, 256, 0, stream>>>(pos, Wp, We, mk, Pmat, Bfrag, flag);
  swizzle_kernel<<<NT, 256, 0, stream>>>(Pmat, Psw);
  fused_kernel<<<BB / 4, 256, 0, stream>>>(Xs, Xi, mk, Wc, zv, Psw, Bfrag, flag, out);
}

// Round 4
// 189.969 us; speedup vs baseline: 1.1040x; 1.0329x over previous
//
#include <hip/hip_runtime.h>

#define BB 4096
#define SS 200
#define DD 128
#define HH 64
#define NT 13            // 13 tiles of 16 rows (208 padded)
#define OUTW (DD + 1)

typedef __attribute__((ext_vector_type(4))) float f32x4;
typedef __attribute__((ext_vector_type(8))) __bf16 bf16x8;

__device__ __forceinline__ short f2b(float f) {        // f32 -> bf16 (RNE)
  unsigned int u = __float_as_uint(f);
  unsigned int r = (u + 0x7FFFu + ((u >> 16) & 1u)) >> 16;
  return (short)r;
}

// ---------------- setup1: P = pos@Wp, We -> MFMA B-frag order, mask dtype probe ----
__global__ void setup_kernel(const float* __restrict__ pos,
                             const float* __restrict__ Wp,
                             const float* __restrict__ We,
                             const void* __restrict__ maskv,
                             float* __restrict__ Pmat,
                             short* __restrict__ Bfrag,
                             int* __restrict__ flag) {
  __shared__ int anyf[4];
  const int blk = blockIdx.x;
  const int t = threadIdx.x;
  if (blk < SS) {
    if (t < HH) {
      float acc = 0.f;
      #pragma unroll 8
      for (int d = 0; d < DD; ++d) acc = fmaf(pos[blk * DD + d], Wp[d * HH + t], acc);
      Pmat[blk * HH + t] = acc;
    }
  } else if (blk == SS) {
    // Bfrag[((ct*4+kt)*64+lane)*8 + j] = bf16(We[kt*32 + 8*(lane>>4) + j][ct*16 + (lane&15)])
    for (int id = t; id < 1024; id += 256) {
      int lane = id & 63;
      int kt = (id >> 6) & 3;
      int ct = id >> 8;
      int kbase = kt * 32 + 8 * (lane >> 4);
      int n = ct * 16 + (lane & 15);
      short* dst = Bfrag + id * 8;
      #pragma unroll
      for (int j = 0; j < 8; ++j) dst[j] = f2b(We[(kbase + j) * HH + n]);
    }
  } else {
    // mask dtype probe: bool8 has nonzero bytes at positions %4!=0; int32(0/1) does not
    const unsigned char* mb = (const unsigned char*)maskv;
    int local = 0;
    for (int i = t; i < 4096; i += 256)
      if ((i & 3) != 0 && mb[i] != 0) local = 1;
    unsigned long long bal = __ballot(local != 0);
    if ((t & 63) == 0) anyf[t >> 6] = (bal != 0ull) ? 1 : 0;
    __syncthreads();
    if (t == 0) *flag = (anyf[0] | anyf[1] | anyf[2] | anyf[3]);
  }
}

// ---------------- setup2: swizzle Pmat into per-lane-contiguous layout -------------
// Psw[(((t*4+lg)*16+lr)*16 + ct*4 + r)] = Pmat[min(t*16+4lg+r,199)][16ct+lr]
__global__ void swizzle_kernel(const float* __restrict__ Pmat, float* __restrict__ Psw) {
  const int t = blockIdx.x;                 // tile 0..12
  const int tid = threadIdx.x;              // 256
  const int lg = tid >> 6, lr = (tid >> 2) & 15, ct = tid & 3;
  f32x4 v;
  #pragma unroll
  for (int r = 0; r < 4; ++r) {
    int s = t * 16 + 4 * lg + r;
    if (s >= SS) s = SS - 1;
    v[r] = Pmat[s * HH + ct * 16 + lr];
  }
  *(f32x4*)&Psw[((t * 4 + lg) * 16 + lr) * 16 + ct * 4] = v;
}

// ---------------- fused: one WAVE per batch row; compute sections touch NO VMEM ----
__global__ __launch_bounds__(256, 3) void fused_kernel(
    const float* __restrict__ Xs, const float* __restrict__ Xi,
    const void* __restrict__ maskv, const float* __restrict__ Wc,
    const float* __restrict__ zv, const float* __restrict__ Psw,
    const short* __restrict__ Bfrag, const int* __restrict__ flagp,
    float* __restrict__ out) {
  __shared__ __align__(16) short bf_lds[16 * 64 * 8];   // 16 KB We B-fragments

  const int t = threadIdx.x;
  const int lane = t & 63;
  const int w = t >> 6;
  const int lg = lane >> 4;
  const int lr = lane & 15;
  const int b = blockIdx.x * 4 + w;

  const float* xb = Xs + (size_t)b * (SS * DD) + lg * 8;

  // ---- issue tile-0 X loads + Psw tile-0 FIRST (latency hides under setup) ----
  f32x4 raw[8];
  {
    const float* rp = xb + (size_t)lr * DD;
    #pragma unroll
    for (int kt = 0; kt < 4; ++kt) {
      raw[2 * kt]     = *(const f32x4*)(rp + kt * 32);
      raw[2 * kt + 1] = *(const f32x4*)(rp + kt * 32 + 4);
    }
  }
  f32x4 pswr[4];
  {
    const f32x4* pp = (const f32x4*)(Psw + (size_t)(lg * 16 + lr) * 16);
    #pragma unroll
    for (int ct = 0; ct < 4; ++ct) pswr[ct] = pp[ct];
  }

  // ---- stage B-fragments into LDS (16 KB, L2/L3-hot) ----
  {
    const f32x4* src = (const f32x4*)Bfrag;
    f32x4* dst = (f32x4*)bf_lds;
    #pragma unroll
    for (int i = 0; i < 4; ++i) dst[t + 256 * i] = src[t + 256 * i];
  }

  // ---- c[h] = Xi[b] . Wc[:,h], h = lane; redistribute c,z to (ct,lr) layout ----
  float c = 0.f;
  {
    const float* xi = Xi + (size_t)b * DD;
    const float* wc = Wc + lane;
    #pragma unroll 8
    for (int d = 0; d < DD; ++d) c = fmaf(xi[d], wc[d * HH], c);
  }

  // ---- per-lane mask bits: bit tt = valid_mask[b][tt*16+lr] ----
  const int mflag = *flagp;
  unsigned mbits = 0;
  if (mflag) {
    const unsigned char* mbp = (const unsigned char*)maskv + (size_t)b * SS;
    #pragma unroll
    for (int tt = 0; tt < NT; ++tt) {
      const int srow = tt * 16 + lr;
      unsigned v = (srow < SS) ? (unsigned)mbp[srow] : 0u;
      mbits |= (v ? 1u : 0u) << tt;
    }
  } else {
    const int* mip = (const int*)maskv + (size_t)b * SS;
    #pragma unroll
    for (int tt = 0; tt < NT; ++tt) {
      const int srow = tt * 16 + lr;
      unsigned v = (srow < SS) ? (unsigned)(mip[srow] != 0) : 0u;
      mbits |= v << tt;
    }
  }

  float c4[4], z4[4];
  {
    const float zl = zv[lane];
    #pragma unroll
    for (int ct = 0; ct < 4; ++ct) {
      c4[ct] = __shfl(c, ct * 16 + lr, 64);
      z4[ct] = __shfl(zl, ct * 16 + lr, 64);
    }
  }
  __syncthreads();

  const bf16x8* bp = (const bf16x8*)bf_lds;
  float part[4][8];
  #pragma unroll
  for (int kt = 0; kt < 4; ++kt)
    #pragma unroll
    for (int j = 0; j < 8; ++j) part[kt][j] = 0.f;
  float usum = 0.f, ssum = 0.f;

  for (int tt = 0; tt < NT; ++tt) {
    // ---- consume prefetched raw/pswr (single vmcnt drain per tile) ----
    bf16x8 af[4];
    #pragma unroll
    for (int kt = 0; kt < 4; ++kt) {
      bf16x8 v;
      v[0] = (__bf16)raw[2*kt][0]; v[1] = (__bf16)raw[2*kt][1];
      v[2] = (__bf16)raw[2*kt][2]; v[3] = (__bf16)raw[2*kt][3];
      v[4] = (__bf16)raw[2*kt+1][0]; v[5] = (__bf16)raw[2*kt+1][1];
      v[6] = (__bf16)raw[2*kt+1][2]; v[7] = (__bf16)raw[2*kt+1][3];
      af[kt] = v;
    }
    f32x4 acc[4];
    #pragma unroll
    for (int ct = 0; ct < 4; ++ct) {
      const f32x4 pv = pswr[ct];
      acc[ct][0] = pv[0] + c4[ct]; acc[ct][1] = pv[1] + c4[ct];
      acc[ct][2] = pv[2] + c4[ct]; acc[ct][3] = pv[3] + c4[ct];
    }
    // ---- prefetch tile t+1 (consumed ONLY next iteration) ----
    if (tt + 1 < NT) {
      int srow = (tt + 1) * 16 + lr;
      if (srow >= SS) srow = SS - 1;                 // clamped rows masked via mbits
      const float* rp = xb + (size_t)srow * DD;
      #pragma unroll
      for (int kt = 0; kt < 4; ++kt) {
        raw[2 * kt]     = *(const f32x4*)(rp + kt * 32);
        raw[2 * kt + 1] = *(const f32x4*)(rp + kt * 32 + 4);
      }
      const f32x4* pp = (const f32x4*)(Psw + (size_t)(((tt + 1) * 4 + lg) * 16 + lr) * 16);
      #pragma unroll
      for (int ct = 0; ct < 4; ++ct) pswr[ct] = pp[ct];
    }
    // ---- compute: MFMA + score epilogue (no VMEM from here to loop end) ----
    #pragma unroll
    for (int kt = 0; kt < 4; ++kt)
      #pragma unroll
      for (int ct = 0; ct < 4; ++ct)
        acc[ct] = __builtin_amdgcn_mfma_f32_16x16x32_bf16(af[kt], bp[(ct * 4 + kt) * 64 + lane],
                                                          acc[ct], 0, 0, 0);
    // scores[s=tt*16+4lg+r] = sum_h z[h]*tanh(pre);  reduce over lr (h-groups)
    float sc[4];
    #pragma unroll
    for (int r = 0; r < 4; ++r) {
      float p = 0.f;
      #pragma unroll
      for (int ct = 0; ct < 4; ++ct) {
        const float e2 = __expf(2.f * acc[ct][r]);
        const float th = 1.f - 2.f * __builtin_amdgcn_rcpf(e2 + 1.f);
        p = fmaf(z4[ct], th, p);
      }
      p += __shfl_xor(p, 1);
      p += __shfl_xor(p, 2);
      p += __shfl_xor(p, 4);
      p += __shfl_xor(p, 8);
      sc[r] = p;      // full score, identical across each 16-lane lr group
    }
    // redistribute: lane needs score of row tt*16+lr (held by lane (lr>>2)*16, reg lr&3)
    #pragma unroll
    for (int r = 0; r < 4; ++r) sc[r] = __shfl(sc[r], (lr >> 2) << 4, 64);
    const float sa = (lr & 1) ? sc[1] : sc[0];
    const float sb = (lr & 1) ? sc[3] : sc[2];
    const float mysc = (lr & 2) ? sb : sa;
    const bool mv = (mbits >> tt) & 1u;
    const float u = mv ? __expf(mysc) : 0.f;    // |score| <= sum|z| ~ 7: no max-sub needed
    ssum += mv ? mysc : 0.f;
    usum += u;
    #pragma unroll
    for (int kt = 0; kt < 4; ++kt)
      #pragma unroll
      for (int j = 0; j < 8; ++j)
        part[kt][j] = fmaf(u, (float)af[kt][j], part[kt][j]);
  }

  // reduce over the 16 lr lanes (rows); each lg group covers distinct cols
  #pragma unroll
  for (int off = 1; off <= 8; off <<= 1) {
    #pragma unroll
    for (int kt = 0; kt < 4; ++kt)
      #pragma unroll
      for (int j = 0; j < 8; ++j)
        part[kt][j] += __shfl_xor(part[kt][j], off);
    usum += __shfl_xor(usum, off);
    ssum += __shfl_xor(ssum, off);
  }
  const float inv = 1.f / usum;
  if (lr == 0) {
    float* ob = out + (size_t)b * OUTW;
    #pragma unroll
    for (int kt = 0; kt < 4; ++kt)
      #pragma unroll
      for (int j = 0; j < 8; ++j)
        ob[kt * 32 + lg * 8 + j] = part[kt][j] * inv;
  }
  if (lane == 8) out[(size_t)b * OUTW + DD] = ssum;
}

extern "C" void kernel_launch(void* const* d_in, const int* in_sizes, int n_in,
                              void* d_out, int out_size, void* d_ws, size_t ws_size,
                              hipStream_t stream) {
  const float* Xs  = (const float*)d_in[0];   // X_series [B,S,D]
  const float* pos = (const float*)d_in[1];   // pos_series [S,D]
  const float* Xi  = (const float*)d_in[2];   // X_item [B,D]
  const void*  mk  = d_in[3];                 // valid_mask [B,S] (bool8 or int32 — probed)
  const float* Wc  = (const float*)d_in[4];
  const float* Wp  = (const float*)d_in[5];
  const float* We  = (const float*)d_in[6];
  const float* zv  = (const float*)d_in[7];
  float* out = (float*)d_out;

  char* ws = (char*)d_ws;
  int*   flag  = (int*)ws;                             // 4 B    @ 0
  float* Pmat  = (float*)(ws + 256);                   // 51200 B
  short* Bfrag = (short*)(ws + 256 + SS * HH * 4);     // 16384 B @ 51456
  float* Psw   = (float*)(ws + 256 + SS * HH * 4 + 16384);  // 53248 B @ 67840 (16B-aligned)

  setup_kernel<<<SS + 2, 256, 0, stream>>>(pos, Wp, We, mk, Pmat, Bfrag, flag);
  swizzle_kernel<<<NT, 256, 0, stream>>>(Pmat, Psw);
  fused_kernel<<<BB / 4, 256, 0, stream>>>(Xs, Xi, mk, Wc, zv, Psw, Bfrag, flag, out);
}